// Round 2
// baseline (406.005 us; speedup 1.0000x reference)
//
#include <hip/hip_runtime.h>
#include <hip/hip_bf16.h>
#include <math.h>

typedef __hip_bfloat16 bf16;

__device__ __forceinline__ float cv(float x) { return x; }
__device__ __forceinline__ float cv(bf16 x)  { return __bfloat162float(x); }

// block-wide sum over 256 threads
__device__ __forceinline__ float block_sum256(float v, float* red) {
    int t = threadIdx.x;
    red[t] = v; __syncthreads();
    for (int st = 128; st > 0; st >>= 1) {
        if (t < st) red[t] += red[t + st];
        __syncthreads();
    }
    float r = red[0]; __syncthreads();
    return r;
}

// ---------------- dtype detector ----------------
// Inspect first 4096 16-bit words of src_flatten (N(0,1) data, large).
// bf16 buffer: all exponent fields <= ~130, no zero words.
// fp32 buffer: low-half words have uniform-random exponent (~45% >= 140).
// fp32-but-bf16-rounded: even words all exactly 0.
// flag = 1 -> treat inputs as fp32; 0 -> bf16.
__global__ __launch_bounds__(256) void k_detect(const unsigned short* __restrict__ w,
                                                int* __restrict__ flag) {
    int t = threadIdx.x;
    int hi = 0, ze = 0;
    for (int i = t; i < 4096; i += 256) {
        unsigned short u = w[i];
        int e = (u >> 7) & 0xFF;
        if (e >= 140) hi++;
        if (((i & 1) == 0) && u == 0) ze++;
    }
    __shared__ int sh[256], sz[256];
    sh[t] = hi; sz[t] = ze; __syncthreads();
    for (int st = 128; st > 0; st >>= 1) {
        if (t < st) { sh[t] += sh[t + st]; sz[t] += sz[t + st]; }
        __syncthreads();
    }
    if (t == 0) flag[0] = (sh[0] > 100 || sz[0] > 900) ? 1 : 0;
}

// ---------------- Stage A: self-attention ----------------

template <typename T>
__device__ void qkv_body(const void* tgtv, const void* qposv, const void* ipwv, const void* ipbv,
                         float* __restrict__ q, float* __restrict__ k, float* __restrict__ v) {
    const T* tgt = (const T*)tgtv; const T* qpos = (const T*)qposv;
    const T* ipw = (const T*)ipwv; const T* ipb = (const T*)ipbv;
    int e = blockIdx.x, t = threadIdx.x;
    __shared__ float sqk[256], stg[256];
    float tg = cv(tgt[e * 256 + t]);
    stg[t] = tg;
    sqk[t] = tg + cv(qpos[e * 256 + t]);
    __syncthreads();
    const T* wq = ipw + (size_t)t * 256;
    const T* wk = ipw + (size_t)(256 + t) * 256;
    const T* wv = ipw + (size_t)(512 + t) * 256;
    float aq = 0.f, ak = 0.f, av = 0.f;
    for (int i = 0; i < 256; i++) {
        float x = sqk[i];
        aq += x * cv(wq[i]);
        ak += x * cv(wk[i]);
        av += stg[i] * cv(wv[i]);
    }
    q[e * 256 + t] = (aq + cv(ipb[t])) * 0.17677669529663687f;  // * 32^-0.5
    k[e * 256 + t] = ak + cv(ipb[256 + t]);
    v[e * 256 + t] = av + cv(ipb[512 + t]);
}

__global__ __launch_bounds__(256) void k_qkv(const void* tgt, const void* qpos,
                                             const void* ipw, const void* ipb,
                                             const int* __restrict__ flag,
                                             float* q, float* k, float* v) {
    if (*flag) qkv_body<float>(tgt, qpos, ipw, ipb, q, k, v);
    else       qkv_body<bf16 >(tgt, qpos, ipw, ipb, q, k, v);
}

// grid E*H=1024, block 128. sa: (E,256)=(E,H,32). ws-only inputs (fp32) — no template.
__global__ __launch_bounds__(128) void k_attn(const float* __restrict__ q,
                                              const float* __restrict__ k,
                                              const float* __restrict__ v,
                                              float* __restrict__ sa) {
    int e = blockIdx.x >> 3, h = blockIdx.x & 7, f = threadIdx.x;
    __shared__ float sc[128], red[128];
    const float* qe = q + e * 256 + h * 32;
    const float* kf = k + f * 256 + h * 32;
    float s = 0.f;
    for (int d = 0; d < 32; d++) s += qe[d] * kf[d];
    red[f] = s; __syncthreads();
    for (int st = 64; st > 0; st >>= 1) { if (f < st) red[f] = fmaxf(red[f], red[f + st]); __syncthreads(); }
    float m = red[0]; __syncthreads();
    float p = expf(s - m);
    red[f] = p; __syncthreads();
    for (int st = 64; st > 0; st >>= 1) { if (f < st) red[f] += red[f + st]; __syncthreads(); }
    float inv = 1.f / red[0];
    sc[f] = p * inv;
    __syncthreads();
    if (f < 32) {
        float acc = 0.f;
        for (int ff = 0; ff < 128; ff++) acc += sc[ff] * v[ff * 256 + h * 32 + f];
        sa[e * 256 + h * 32 + f] = acc;
    }
}

template <typename T>
__device__ void projnorm2_body(const float* __restrict__ sa, const void* tgtv, const void* opwv,
                               const void* opbv, const void* nwv, const void* nbv,
                               float* __restrict__ xout) {
    const T* tgt = (const T*)tgtv; const T* opw = (const T*)opwv; const T* opb = (const T*)opbv;
    const T* nw = (const T*)nwv; const T* nb = (const T*)nbv;
    int e = blockIdx.x, t = threadIdx.x;
    __shared__ float row[256], red[256];
    row[t] = sa[e * 256 + t]; __syncthreads();
    const T* w = opw + (size_t)t * 256;
    float acc = cv(opb[t]) + cv(tgt[e * 256 + t]);
    for (int i = 0; i < 256; i++) acc += row[i] * cv(w[i]);
    float mean = block_sum256(acc, red) * (1.f / 256.f);
    float d0 = acc - mean;
    float var = block_sum256(d0 * d0, red) * (1.f / 256.f);
    xout[e * 256 + t] = d0 * rsqrtf(var + 1e-5f) * cv(nw[t]) + cv(nb[t]);
}

__global__ __launch_bounds__(256) void k_projnorm2(const float* sa, const void* tgt,
                                                   const void* opw, const void* opb,
                                                   const void* nw, const void* nb,
                                                   const int* __restrict__ flag, float* xout) {
    if (*flag) projnorm2_body<float>(sa, tgt, opw, opb, nw, nb, xout);
    else       projnorm2_body<bf16 >(sa, tgt, opw, opb, nw, nb, xout);
}

// ---------------- Stage B: geometry + pos-encode ----------------

template <typename T>
__device__ void geom_body(const void* ecv, float* __restrict__ pe, float* __restrict__ ref,
                          int* __restrict__ lxly) {
    const T* ec = (const T*)ecv;
    int n = blockIdx.x, t = threadIdx.x;
    int e = n / 3, j = n - e * 3;
    float ax = cv(ec[e * 4 + 0]), ay = cv(ec[e * 4 + 1]);
    float bx = cv(ec[e * 4 + 2]), by = cv(ec[e * 4 + 3]);
    float tj = 0.5f * (float)j;
    float dx = bx - ax, dy = by - ay;
    float ptx = __fadd_rn(ax, __fmul_rn(tj, dx));
    float pty = __fadd_rn(ay, __fmul_rn(tj, dy));
    float cxf = floorf(ptx), cyf = floorf(pty);
    int icx = (int)cxf, icy = (int)cyf;
    int minx = max(icx - 128, 0); if (minx + 256 > 2048) minx = 2048 - 256;
    int miny = max(icy - 128, 0); if (miny + 256 > 2048) miny = 2048 - 256;
    float fminx = (float)minx, fminy = (float)miny;
    float tlx, thx, tly, thy;
    if (dx == 0.f) { tlx = 0.f; thx = 1.f; }
    else { float u1 = (fminx - ax) / dx, u2 = (fminx + 256.f - ax) / dx; tlx = fminf(u1, u2); thx = fmaxf(u1, u2); }
    if (dy == 0.f) { tly = 0.f; thy = 1.f; }
    else { float u1 = (fminy - ay) / dy, u2 = (fminy + 256.f - ay) / dy; tly = fminf(u1, u2); thy = fmaxf(u1, u2); }
    float t0 = fmaxf(fmaxf(tlx, tly), 0.f);
    float t1 = fmaxf(fminf(fminf(thx, thy), 1.f), t0);
    float pxs[3], pys[3];
    pxs[0] = __fadd_rn(ax, __fmul_rn(t0, dx)); pys[0] = __fadd_rn(ay, __fmul_rn(t0, dy));
    pxs[1] = __fadd_rn(ax, __fmul_rn(t1, dx)); pys[1] = __fadd_rn(ay, __fmul_rn(t1, dy));
    pxs[2] = cxf; pys[2] = cyf;
    int i = t & 63, kk = i >> 1;
    float invd = expf(-(float)kk * (9.210340371976184f / 32.f));  // 10000^(-kk/32)
    for (int jj = 0; jj < 3; jj++) {
        float vv = (t < 64) ? pys[jj] : pxs[jj];  // enc(y) first, then enc(x)
        float p = vv * invd;
        pe[n * 384 + jj * 128 + t] = (i & 1) ? cosf(p) : sinf(p);
    }
    if (t == 0) {
        ref[n * 2 + 0] = (cxf - fminx) * (1.f / 256.f);
        ref[n * 2 + 1] = (cyf - fminy) * (1.f / 256.f);
        lxly[n * 8 + 0] = (int)rintf(fminx * 0.125f);
        lxly[n * 8 + 1] = (int)rintf(fminx * 0.0625f);
        lxly[n * 8 + 2] = (int)rintf(fminx * 0.03125f);
        lxly[n * 8 + 3] = (int)rintf(fminx * 0.015625f);
        lxly[n * 8 + 4] = (int)rintf(fminy * 0.125f);
        lxly[n * 8 + 5] = (int)rintf(fminy * 0.0625f);
        lxly[n * 8 + 6] = (int)rintf(fminy * 0.03125f);
        lxly[n * 8 + 7] = (int)rintf(fminy * 0.015625f);
    }
}

__global__ __launch_bounds__(128) void k_geom(const void* ec, const int* __restrict__ flag,
                                              float* pe, float* ref, int* lxly) {
    if (*flag) geom_body<float>(ec, pe, ref, lxly);
    else       geom_body<bf16 >(ec, pe, ref, lxly);
}

template <typename T>
__device__ void nq_body(const float* __restrict__ x1, const void* qposv, const float* __restrict__ pe,
                        const void* l0wv, const void* l0bv, float* __restrict__ nq) {
    const T* qpos = (const T*)qposv; const T* l0w = (const T*)l0wv; const T* l0b = (const T*)l0bv;
    int n = blockIdx.x, t = threadIdx.x, e = n / 3;
    __shared__ float feat[640];
    feat[t] = x1[e * 256 + t] + cv(qpos[e * 256 + t]);
    feat[256 + t] = pe[n * 384 + t];
    if (t < 128) feat[512 + t] = pe[n * 384 + 256 + t];
    __syncthreads();
    const T* w = l0w + (size_t)t * 640;
    float acc = cv(l0b[t]);
    for (int i = 0; i < 640; i++) acc += feat[i] * cv(w[i]);
    nq[n * 256 + t] = acc;
}

__global__ __launch_bounds__(256) void k_nq(const float* x1, const void* qpos, const float* pe,
                                            const void* l0w, const void* l0b,
                                            const int* __restrict__ flag, float* nq) {
    if (*flag) nq_body<float>(x1, qpos, pe, l0w, l0b, nq);
    else       nq_body<bf16 >(x1, qpos, pe, l0w, l0b, nq);
}

template <typename T>
__device__ void offaw_body(const float* __restrict__ nq, const void* offwv, const void* offbv,
                           const void* awwv, const void* awbv, const float* __restrict__ ref,
                           const void* vrv, float* __restrict__ aw, float* __restrict__ loc) {
    const T* offw = (const T*)offwv; const T* offb = (const T*)offbv;
    const T* aww = (const T*)awwv; const T* awb = (const T*)awbv; const T* vr = (const T*)vrv;
    int n = blockIdx.x, t = threadIdx.x;
    __shared__ float row[256], offs[256], atr[128];
    row[t] = nq[n * 256 + t]; __syncthreads();
    {
        const T* w = offw + (size_t)t * 256;
        float acc = cv(offb[t]);
        for (int i = 0; i < 256; i++) acc += row[i] * cv(w[i]);
        offs[t] = acc;
    }
    if (t < 128) {
        const T* w = aww + (size_t)t * 256;
        float acc = cv(awb[t]);
        for (int i = 0; i < 256; i++) acc += row[i] * cv(w[i]);
        atr[t] = acc;
    }
    __syncthreads();
    if (t < 8) {
        float m = -1e30f;
        for (int i = 0; i < 16; i++) m = fmaxf(m, atr[t * 16 + i]);
        float p[16], s = 0.f;
        for (int i = 0; i < 16; i++) { p[i] = expf(atr[t * 16 + i] - m); s += p[i]; }
        float inv = 1.f / s;
        for (int i = 0; i < 16; i++) aw[n * 128 + t * 16 + i] = p[i] * inv;
    }
    int rem = t & 31, l = rem >> 3, c = t & 1;
    float slv = (float)(32 >> l);
    float refc = ref[n * 2 + c] * cv(vr[l * 2 + c]);
    loc[n * 256 + t] = refc + offs[t] / slv;
}

__global__ __launch_bounds__(256) void k_offaw(const float* nq, const void* offw, const void* offb,
                                               const void* aww, const void* awb, const float* ref,
                                               const void* vr, const int* __restrict__ flag,
                                               float* aw, float* loc) {
    if (*flag) offaw_body<float>(nq, offw, offb, aww, awb, ref, vr, aw, loc);
    else       offaw_body<bf16 >(nq, offw, offb, aww, awb, ref, vr, aw, loc);
}

// ---------------- Stage C: deformable sampling (linearity-fused) ----------------

template <typename T>
__device__ void sample_body(const float* __restrict__ aw, const float* __restrict__ loc,
                            const int* __restrict__ lxly, const void* srcv,
                            const unsigned char* __restrict__ mask, const void* valwv,
                            const void* valbv, float* __restrict__ ca) {
    const T* src = (const T*)srcv; const T* valw = (const T*)valwv; const T* valb = (const T*)valbv;
    int n = blockIdx.x >> 3, h = blockIdx.x & 7, t = threadIdx.x;
    __shared__ float cw[64];
    __shared__ int cg[64];
    __shared__ float agg[256];
    if (t < 64) {
        int l = t >> 4, p = (t >> 2) & 3, tap = t & 3;
        int s = 32 >> l;
        int wl = 256 >> l;
        const int img_starts[4] = {0, 65536, 81920, 86016};
        float a = aw[n * 128 + h * 16 + l * 4 + p];
        float gx = loc[n * 256 + h * 32 + l * 8 + p * 2 + 0];
        float gy = loc[n * 256 + h * 32 + l * 8 + p * 2 + 1];
        float px = gx * (float)s - 0.5f, py = gy * (float)s - 0.5f;
        float x0 = floorf(px), y0 = floorf(py);
        float fx = px - x0, fy = py - y0;
        int xi = (int)x0 + (tap & 1), yi = (int)y0 + (tap >> 1);
        float wt = ((tap & 1) ? fx : (1.f - fx)) * ((tap >> 1) ? fy : (1.f - fy));
        int g = -1;
        if (xi >= 0 && xi < s && yi >= 0 && yi < s) {
            int col = lxly[n * 8 + l] + xi;
            int row = lxly[n * 8 + 4 + l] + yi;
            g = img_starts[l] + row * wl + col;
            if (mask[g]) g = -1;
        }
        cw[t] = a * wt;
        cg[t] = g;
    }
    __syncthreads();
    float acc = 0.f, csum = 0.f;
    for (int tp = 0; tp < 64; tp++) {
        int g = cg[tp];
        if (g >= 0) {
            acc += cw[tp] * cv(src[(size_t)g * 256 + t]);
            csum += cw[tp];
        }
    }
    agg[t] = acc;
    __syncthreads();
    if (t < 32) {
        const T* w = valw + (size_t)(h * 32 + t) * 256;
        float o = 0.f;
        for (int i = 0; i < 256; i++) o += agg[i] * cv(w[i]);
        ca[n * 256 + h * 32 + t] = o + csum * cv(valb[h * 32 + t]);
    }
}

__global__ __launch_bounds__(256) void k_sample(const float* aw, const float* loc, const int* lxly,
                                                const void* src, const unsigned char* mask,
                                                const void* valw, const void* valb,
                                                const int* __restrict__ flag, float* ca) {
    if (*flag) sample_body<float>(aw, loc, lxly, src, mask, valw, valb, ca);
    else       sample_body<bf16 >(aw, loc, lxly, src, mask, valw, valb, ca);
}

template <typename T>
__device__ void poolnorm1_body(const float* __restrict__ ca, const float* __restrict__ x1,
                               const void* ojwv, const void* ojbv, const void* nwv, const void* nbv,
                               float* __restrict__ x2) {
    const T* ojw = (const T*)ojwv; const T* ojb = (const T*)ojbv;
    const T* nw = (const T*)nwv; const T* nb = (const T*)nbv;
    int e = blockIdx.x, t = threadIdx.x;
    __shared__ float row[256], red[256];
    row[t] = (ca[(3 * e) * 256 + t] + ca[(3 * e + 1) * 256 + t] + ca[(3 * e + 2) * 256 + t]) * (1.f / 3.f);
    __syncthreads();
    const T* w = ojw + (size_t)t * 256;
    float acc = cv(ojb[t]) + x1[e * 256 + t];
    for (int i = 0; i < 256; i++) acc += row[i] * cv(w[i]);
    float mean = block_sum256(acc, red) * (1.f / 256.f);
    float d0 = acc - mean;
    float var = block_sum256(d0 * d0, red) * (1.f / 256.f);
    x2[e * 256 + t] = d0 * rsqrtf(var + 1e-5f) * cv(nw[t]) + cv(nb[t]);
}

__global__ __launch_bounds__(256) void k_poolnorm1(const float* ca, const float* x1,
                                                   const void* ojw, const void* ojb,
                                                   const void* nw, const void* nb,
                                                   const int* __restrict__ flag, float* x2) {
    if (*flag) poolnorm1_body<float>(ca, x1, ojw, ojb, nw, nb, x2);
    else       poolnorm1_body<bf16 >(ca, x1, ojw, ojb, nw, nb, x2);
}

// ---------------- Stage D: FFN ----------------

template <typename T>
__device__ void ffn1_body(const float* __restrict__ x2, const void* w1v, const void* b1v,
                          float* __restrict__ h1) {
    const T* w1 = (const T*)w1v; const T* b1 = (const T*)b1v;
    int e = blockIdx.x, t = threadIdx.x;
    __shared__ float row[256];
    if (t < 256) row[t] = x2[e * 256 + t];
    __syncthreads();
    const T* w = w1 + (size_t)t * 256;
    float acc = cv(b1[t]);
    for (int i = 0; i < 256; i++) acc += row[i] * cv(w[i]);
    h1[e * 1024 + t] = fmaxf(acc, 0.f);
}

__global__ __launch_bounds__(1024) void k_ffn1(const float* x2, const void* w1, const void* b1,
                                               const int* __restrict__ flag, float* h1) {
    if (*flag) ffn1_body<float>(x2, w1, b1, h1);
    else       ffn1_body<bf16 >(x2, w1, b1, h1);
}

template <typename T>
__device__ void ffn2_body(const float* __restrict__ h1, const float* __restrict__ x2,
                          const void* w2v, const void* b2v, const void* nwv, const void* nbv,
                          void* outv) {
    const T* w2 = (const T*)w2v; const T* b2 = (const T*)b2v;
    const T* nw = (const T*)nwv; const T* nb = (const T*)nbv;
    T* out = (T*)outv;
    int e = blockIdx.x, t = threadIdx.x;
    __shared__ float row[1024], red[256];
    for (int i = t; i < 1024; i += 256) row[i] = h1[e * 1024 + i];
    __syncthreads();
    const T* w = w2 + (size_t)t * 1024;
    float acc = cv(b2[t]) + x2[e * 256 + t];
    for (int i = 0; i < 1024; i++) acc += row[i] * cv(w[i]);
    float mean = block_sum256(acc, red) * (1.f / 256.f);
    float d0 = acc - mean;
    float var = block_sum256(d0 * d0, red) * (1.f / 256.f);
    float r = d0 * rsqrtf(var + 1e-5f) * cv(nw[t]) + cv(nb[t]);
    out[e * 256 + t] = (T)r;
}

__global__ __launch_bounds__(256) void k_ffn2(const float* h1, const float* x2, const void* w2,
                                              const void* b2, const void* nw, const void* nb,
                                              const int* __restrict__ flag, void* out) {
    if (*flag) ffn2_body<float>(h1, x2, w2, b2, nw, nb, out);
    else       ffn2_body<bf16 >(h1, x2, w2, b2, nw, nb, out);
}

extern "C" void kernel_launch(void* const* d_in, const int* in_sizes, int n_in,
                              void* d_out, int out_size, void* d_ws, size_t ws_size,
                              hipStream_t stream) {
    (void)in_sizes; (void)n_in; (void)out_size; (void)ws_size;
    const void* tgt  = d_in[0];
    const void* qpos = d_in[1];
    const void* ec   = d_in[2];
    const void* src  = d_in[3];
    const unsigned char* mask = (const unsigned char*)d_in[4];
    const void* vr   = d_in[5];
    const void* ipw  = d_in[6];
    const void* ipb  = d_in[7];
    const void* opw  = d_in[8];
    const void* opb  = d_in[9];
    const void* n1w  = d_in[10];
    const void* n1b  = d_in[11];
    const void* n2w  = d_in[12];
    const void* n2b  = d_in[13];
    const void* n3w  = d_in[14];
    const void* n3b  = d_in[15];
    const void* l0w  = d_in[16];
    const void* l0b  = d_in[17];
    const void* l1w  = d_in[18];
    const void* l1b  = d_in[19];
    const void* l2w  = d_in[20];
    const void* l2b  = d_in[21];
    const void* offw = d_in[22];
    const void* offb = d_in[23];
    const void* aww  = d_in[24];
    const void* awb  = d_in[25];
    const void* valw = d_in[26];
    const void* valb = d_in[27];
    const void* ojw  = d_in[28];
    const void* ojb  = d_in[29];

    float* ws  = (float*)d_ws;
    float* q   = ws;            // 32768
    float* k   = ws + 32768;    // 32768
    float* v   = ws + 65536;    // 32768
    float* sa  = ws + 98304;    // 32768
    float* x1  = ws + 131072;   // 32768
    float* pe  = ws + 163840;   // 147456
    float* nq  = ws + 311296;   // 98304
    float* aw  = ws + 409600;   // 49152
    float* loc = ws + 458752;   // 98304
    float* ca  = ws + 557056;   // 98304
    float* x2  = ws + 655360;   // 32768
    float* h1  = ws + 688128;   // 131072
    float* ref = ws + 819200;   // 768
    int*   lxly = (int*)(ws + 819968); // 3072 ints
    int*   flag = (int*)(ws + 823040); // 1 int

    k_detect<<<1, 256, 0, stream>>>((const unsigned short*)src, flag);
    k_qkv<<<128, 256, 0, stream>>>(tgt, qpos, ipw, ipb, flag, q, k, v);
    k_attn<<<1024, 128, 0, stream>>>(q, k, v, sa);
    k_projnorm2<<<128, 256, 0, stream>>>(sa, tgt, opw, opb, n2w, n2b, flag, x1);
    k_geom<<<384, 128, 0, stream>>>(ec, flag, pe, ref, lxly);
    k_nq<<<384, 256, 0, stream>>>(x1, qpos, pe, l0w, l0b, flag, nq);
    k_offaw<<<384, 256, 0, stream>>>(nq, offw, offb, aww, awb, ref, vr, flag, aw, loc);
    k_sample<<<3072, 256, 0, stream>>>(aw, loc, lxly, src, mask, valw, valb, flag, ca);
    k_poolnorm1<<<128, 256, 0, stream>>>(ca, x1, ojw, ojb, n1w, n1b, flag, x2);
    k_ffn1<<<128, 1024, 0, stream>>>(x2, l1w, l1b, flag, h1);
    k_ffn2<<<128, 256, 0, stream>>>(h1, x2, l2w, l2b, n3w, n3b, flag, d_out);
}

// Round 3
// 393.309 us; speedup vs baseline: 1.0323x; 1.0323x over previous
//
#include <hip/hip_runtime.h>
#include <math.h>

// All inputs/outputs are fp32 (verified R2: absmax 1.95e-3 << bf16 output
// quantization floor 0.0156, and the bf16-misread path provably NaNs).

// block-wide sum over 256 threads
__device__ __forceinline__ float block_sum256(float v, float* red) {
    int t = threadIdx.x;
    red[t] = v; __syncthreads();
    for (int st = 128; st > 0; st >>= 1) {
        if (t < st) red[t] += red[t + st];
        __syncthreads();
    }
    float r = red[0]; __syncthreads();
    return r;
}

// ---------------- 1: QKV projection ----------------
// grid 128 (per edge), block 256
__global__ __launch_bounds__(256) void k_qkv(const float* __restrict__ tgt,
                                             const float* __restrict__ qpos,
                                             const float* __restrict__ ipw,
                                             const float* __restrict__ ipb,
                                             float* __restrict__ q,
                                             float* __restrict__ k,
                                             float* __restrict__ v) {
    int e = blockIdx.x, t = threadIdx.x;
    __shared__ float sqk[256], stg[256];
    float tg = tgt[e * 256 + t];
    stg[t] = tg;
    sqk[t] = tg + qpos[e * 256 + t];
    __syncthreads();
    const float* wq = ipw + (size_t)t * 256;
    const float* wk = ipw + (size_t)(256 + t) * 256;
    const float* wv = ipw + (size_t)(512 + t) * 256;
    float aq = 0.f, ak = 0.f, av = 0.f;
    for (int i = 0; i < 256; i++) {
        float x = sqk[i];
        aq += x * wq[i];
        ak += x * wk[i];
        av += stg[i] * wv[i];
    }
    q[e * 256 + t] = (aq + ipb[t]) * 0.17677669529663687f;  // * 32^-0.5
    k[e * 256 + t] = ak + ipb[256 + t];
    v[e * 256 + t] = av + ipb[512 + t];
}

// ---------------- 2: attention + out-proj + norm2 ----------------
// grid 128 (per edge), block 256. x1: (E,256)
__global__ __launch_bounds__(256) void k_attn_norm(const float* __restrict__ q,
                                                   const float* __restrict__ k,
                                                   const float* __restrict__ v,
                                                   const float* __restrict__ tgt,
                                                   const float* __restrict__ opw,
                                                   const float* __restrict__ opb,
                                                   const float* __restrict__ nw,
                                                   const float* __restrict__ nb,
                                                   float* __restrict__ x1) {
    int e = blockIdx.x, t = threadIdx.x;
    __shared__ float sq[256];      // q[e]
    __shared__ float sS[1024];     // scores [h][f]
    __shared__ float srow[256], red[256];
    __shared__ float smax[8], ssum[8];
    sq[t] = q[e * 256 + t];
    __syncthreads();
    for (int it = 0; it < 4; it++) {
        int idx = it * 256 + t, h = idx >> 7, f = idx & 127;
        const float* kf = k + f * 256 + h * 32;
        const float* qh = sq + h * 32;
        float s = 0.f;
        for (int d = 0; d < 32; d++) s += qh[d] * kf[d];
        sS[idx] = s;
    }
    __syncthreads();
    if (t < 8) {
        float m = -1e30f;
        for (int f = 0; f < 128; f++) m = fmaxf(m, sS[t * 128 + f]);
        smax[t] = m;
    }
    __syncthreads();
    for (int it = 0; it < 4; it++) {
        int idx = it * 256 + t, h = idx >> 7;
        sS[idx] = __expf(sS[idx] - smax[h]);
    }
    __syncthreads();
    if (t < 8) {
        float s = 0.f;
        for (int f = 0; f < 128; f++) s += sS[t * 128 + f];
        ssum[t] = 1.f / s;
    }
    __syncthreads();
    {
        int h = t >> 5, d = t & 31;
        float inv = ssum[h];
        float acc = 0.f;
        for (int f = 0; f < 128; f++) acc += sS[h * 128 + f] * v[f * 256 + h * 32 + d];
        srow[t] = acc * inv;
    }
    __syncthreads();
    const float* w = opw + (size_t)t * 256;
    float acc = opb[t] + tgt[e * 256 + t];
    for (int i = 0; i < 256; i++) acc += srow[i] * w[i];
    float mean = block_sum256(acc, red) * (1.f / 256.f);
    float d0 = acc - mean;
    float var = block_sum256(d0 * d0, red) * (1.f / 256.f);
    x1[e * 256 + t] = d0 * rsqrtf(var + 1e-5f) * nw[t] + nb[t];
}

// ---------------- 3: geometry + pos-encode + lin0 + off/attw ----------------
// grid 384 (per point), block 256. Outputs aw:(N,128), loc:(N,256), lxly:(N,8)
__global__ __launch_bounds__(256) void k_geo_nq_offaw(const float* __restrict__ ec,
                                                      const float* __restrict__ x1,
                                                      const float* __restrict__ qpos,
                                                      const float* __restrict__ l0w,
                                                      const float* __restrict__ l0b,
                                                      const float* __restrict__ offw,
                                                      const float* __restrict__ offb,
                                                      const float* __restrict__ aww,
                                                      const float* __restrict__ awb,
                                                      const float* __restrict__ vr,
                                                      float* __restrict__ aw,
                                                      float* __restrict__ loc,
                                                      int* __restrict__ lxly) {
    int n = blockIdx.x, t = threadIdx.x;
    int e = n / 3, j = n - e * 3;
    // ---- geometry (redundant per thread; cheap scalar work) ----
    float ax = ec[e * 4 + 0], ay = ec[e * 4 + 1];
    float bx = ec[e * 4 + 2], by = ec[e * 4 + 3];
    float tj = 0.5f * (float)j;
    float dx = bx - ax, dy = by - ay;
    float ptx = __fadd_rn(ax, __fmul_rn(tj, dx));
    float pty = __fadd_rn(ay, __fmul_rn(tj, dy));
    float cxf = floorf(ptx), cyf = floorf(pty);
    int minx = max((int)cxf - 128, 0); if (minx + 256 > 2048) minx = 2048 - 256;
    int miny = max((int)cyf - 128, 0); if (miny + 256 > 2048) miny = 2048 - 256;
    float fminx = (float)minx, fminy = (float)miny;
    float tlx, thx, tly, thy;
    if (dx == 0.f) { tlx = 0.f; thx = 1.f; }
    else { float u1 = (fminx - ax) / dx, u2 = (fminx + 256.f - ax) / dx; tlx = fminf(u1, u2); thx = fmaxf(u1, u2); }
    if (dy == 0.f) { tly = 0.f; thy = 1.f; }
    else { float u1 = (fminy - ay) / dy, u2 = (fminy + 256.f - ay) / dy; tly = fminf(u1, u2); thy = fmaxf(u1, u2); }
    float t0 = fmaxf(fmaxf(tlx, tly), 0.f);
    float t1 = fmaxf(fminf(fminf(thx, thy), 1.f), t0);
    float pxs[3], pys[3];
    pxs[0] = __fadd_rn(ax, __fmul_rn(t0, dx)); pys[0] = __fadd_rn(ay, __fmul_rn(t0, dy));
    pxs[1] = __fadd_rn(ax, __fmul_rn(t1, dx)); pys[1] = __fadd_rn(ay, __fmul_rn(t1, dy));
    pxs[2] = cxf; pys[2] = cyf;
    if (t == 0) {
        lxly[n * 8 + 0] = (int)rintf(fminx * 0.125f);
        lxly[n * 8 + 1] = (int)rintf(fminx * 0.0625f);
        lxly[n * 8 + 2] = (int)rintf(fminx * 0.03125f);
        lxly[n * 8 + 3] = (int)rintf(fminx * 0.015625f);
        lxly[n * 8 + 4] = (int)rintf(fminy * 0.125f);
        lxly[n * 8 + 5] = (int)rintf(fminy * 0.0625f);
        lxly[n * 8 + 6] = (int)rintf(fminy * 0.03125f);
        lxly[n * 8 + 7] = (int)rintf(fminy * 0.015625f);
    }
    // ---- feat = [x1[e]+qpos[e] (256), pe (384)] ----
    __shared__ float feat[640];
    __shared__ float nrow[256], offs[256], atr[128];
    feat[t] = x1[e * 256 + t] + qpos[e * 256 + t];
    // pe(idx): idx in [0,384); jj=idx>>7 selects interp point; tt=idx&127
    #pragma unroll
    for (int rep = 0; rep < 2; rep++) {
        int idx = rep * 256 + t;
        if (idx < 384) {
            int jj = idx >> 7, tt = idx & 127, i = tt & 63, kk = i >> 1;
            float invd = __expf(-(float)kk * (9.210340371976184f / 32.f));  // 10000^(-kk/32)
            float vv = (tt < 64) ? pys[jj] : pxs[jj];
            float p = vv * invd;
            feat[256 + idx] = (i & 1) ? __cosf(p) : __sinf(p);
        }
    }
    __syncthreads();
    // ---- nq = feat @ lin0^T + b ----
    {
        const float* w = l0w + (size_t)t * 640;
        float acc = l0b[t];
        for (int i = 0; i < 640; i++) acc += feat[i] * w[i];
        nrow[t] = acc;
    }
    __syncthreads();
    // ---- off / attw matvecs ----
    {
        const float* w = offw + (size_t)t * 256;
        float acc = offb[t];
        for (int i = 0; i < 256; i++) acc += nrow[i] * w[i];
        offs[t] = acc;
    }
    if (t < 128) {
        const float* w = aww + (size_t)t * 256;
        float acc = awb[t];
        for (int i = 0; i < 256; i++) acc += nrow[i] * w[i];
        atr[t] = acc;
    }
    __syncthreads();
    if (t < 8) {
        float m = -1e30f;
        for (int i = 0; i < 16; i++) m = fmaxf(m, atr[t * 16 + i]);
        float p[16], s = 0.f;
        for (int i = 0; i < 16; i++) { p[i] = __expf(atr[t * 16 + i] - m); s += p[i]; }
        float inv = 1.f / s;
        for (int i = 0; i < 16; i++) aw[n * 128 + t * 16 + i] = p[i] * inv;
    }
    // loc index t = h*32 + l*8 + p*2 + c
    int rem = t & 31, l = rem >> 3, c = t & 1;
    float slv = (float)(32 >> l);
    float ref_c = ((c == 0) ? (cxf - fminx) : (cyf - fminy)) * (1.f / 256.f);
    loc[n * 256 + t] = ref_c * vr[l * 2 + c] + offs[t] / slv;
}

// ---------------- 4: deformable sampling (linearity-fused) ----------------
// grid N*H=3072, block 256. ca:(N,256)
__global__ __launch_bounds__(256) void k_sample(const float* __restrict__ aw,
                                                const float* __restrict__ loc,
                                                const int* __restrict__ lxly,
                                                const float* __restrict__ src,
                                                const unsigned char* __restrict__ mask,
                                                const float* __restrict__ valw,
                                                const float* __restrict__ valb,
                                                float* __restrict__ ca) {
    int n = blockIdx.x >> 3, h = blockIdx.x & 7, t = threadIdx.x;
    __shared__ float cw[64];
    __shared__ int cg[64];
    __shared__ float agg[256];
    if (t < 64) {
        int l = t >> 4, p = (t >> 2) & 3, tap = t & 3;
        int s = 32 >> l;
        int wl = 256 >> l;
        const int img_starts[4] = {0, 65536, 81920, 86016};
        float a = aw[n * 128 + h * 16 + l * 4 + p];
        float gx = loc[n * 256 + h * 32 + l * 8 + p * 2 + 0];
        float gy = loc[n * 256 + h * 32 + l * 8 + p * 2 + 1];
        float px = gx * (float)s - 0.5f, py = gy * (float)s - 0.5f;
        float x0 = floorf(px), y0 = floorf(py);
        float fx = px - x0, fy = py - y0;
        int xi = (int)x0 + (tap & 1), yi = (int)y0 + (tap >> 1);
        float wt = ((tap & 1) ? fx : (1.f - fx)) * ((tap >> 1) ? fy : (1.f - fy));
        int g = -1;
        if (xi >= 0 && xi < s && yi >= 0 && yi < s) {
            int col = lxly[n * 8 + l] + xi;
            int row = lxly[n * 8 + 4 + l] + yi;
            g = img_starts[l] + row * wl + col;
            if (mask[g]) g = -1;  // masked rows zeroed (incl. bias)
        }
        cw[t] = a * wt;
        cg[t] = g;
    }
    __syncthreads();
    float acc = 0.f, csum = 0.f;
    for (int tp = 0; tp < 64; tp++) {
        int g = cg[tp];
        if (g >= 0) {
            acc += cw[tp] * src[(size_t)g * 256 + t];
            csum += cw[tp];
        }
    }
    agg[t] = acc;
    __syncthreads();
    if (t < 32) {
        const float* w = valw + (size_t)(h * 32 + t) * 256;
        float o = 0.f;
        for (int i = 0; i < 256; i++) o += agg[i] * w[i];
        ca[n * 256 + h * 32 + t] = o + csum * valb[h * 32 + t];
    }
}

// ---------------- 5: pool + oproj + norm1 + FFN + norm3 ----------------
// grid 128 (per edge), block 256. out fp32.
__global__ __launch_bounds__(256) void k_tail(const float* __restrict__ ca,
                                              const float* __restrict__ x1,
                                              const float* __restrict__ ojw,
                                              const float* __restrict__ ojb,
                                              const float* __restrict__ n1w,
                                              const float* __restrict__ n1b,
                                              const float* __restrict__ l1w,
                                              const float* __restrict__ l1b,
                                              const float* __restrict__ l2w,
                                              const float* __restrict__ l2b,
                                              const float* __restrict__ n3w,
                                              const float* __restrict__ n3b,
                                              float* __restrict__ out) {
    int e = blockIdx.x, t = threadIdx.x;
    __shared__ float row[256], red[256], x2s[256], h1s[1024];
    row[t] = (ca[(3 * e) * 256 + t] + ca[(3 * e + 1) * 256 + t] + ca[(3 * e + 2) * 256 + t]) * (1.f / 3.f);
    __syncthreads();
    // oproj + residual + norm1
    {
        const float* w = ojw + (size_t)t * 256;
        float acc = ojb[t] + x1[e * 256 + t];
        for (int i = 0; i < 256; i++) acc += row[i] * w[i];
        float mean = block_sum256(acc, red) * (1.f / 256.f);
        float d0 = acc - mean;
        float var = block_sum256(d0 * d0, red) * (1.f / 256.f);
        x2s[t] = d0 * rsqrtf(var + 1e-5f) * n1w[t] + n1b[t];
    }
    __syncthreads();
    // FFN1: 4 rows per thread
    for (int r = 0; r < 4; r++) {
        int o = r * 256 + t;
        const float* w = l1w + (size_t)o * 256;
        float acc = l1b[o];
        for (int i = 0; i < 256; i++) acc += x2s[i] * w[i];
        h1s[o] = fmaxf(acc, 0.f);
    }
    __syncthreads();
    // FFN2 + residual + norm3
    {
        const float* w = l2w + (size_t)t * 1024;
        float acc = l2b[t] + x2s[t];
        for (int i = 0; i < 1024; i++) acc += h1s[i] * w[i];
        float mean = block_sum256(acc, red) * (1.f / 256.f);
        float d0 = acc - mean;
        float var = block_sum256(d0 * d0, red) * (1.f / 256.f);
        out[e * 256 + t] = d0 * rsqrtf(var + 1e-5f) * n3w[t] + n3b[t];
    }
}

extern "C" void kernel_launch(void* const* d_in, const int* in_sizes, int n_in,
                              void* d_out, int out_size, void* d_ws, size_t ws_size,
                              hipStream_t stream) {
    (void)in_sizes; (void)n_in; (void)out_size; (void)ws_size;
    const float* tgt  = (const float*)d_in[0];
    const float* qpos = (const float*)d_in[1];
    const float* ec   = (const float*)d_in[2];
    const float* src  = (const float*)d_in[3];
    const unsigned char* mask = (const unsigned char*)d_in[4];
    const float* vr   = (const float*)d_in[5];
    const float* ipw  = (const float*)d_in[6];
    const float* ipb  = (const float*)d_in[7];
    const float* opw  = (const float*)d_in[8];
    const float* opb  = (const float*)d_in[9];
    const float* n1w  = (const float*)d_in[10];
    const float* n1b  = (const float*)d_in[11];
    const float* n2w  = (const float*)d_in[12];
    const float* n2b  = (const float*)d_in[13];
    const float* n3w  = (const float*)d_in[14];
    const float* n3b  = (const float*)d_in[15];
    const float* l0w  = (const float*)d_in[16];
    const float* l0b  = (const float*)d_in[17];
    const float* l1w  = (const float*)d_in[18];
    const float* l1b  = (const float*)d_in[19];
    const float* l2w  = (const float*)d_in[20];
    const float* l2b  = (const float*)d_in[21];
    const float* offw = (const float*)d_in[22];
    const float* offb = (const float*)d_in[23];
    const float* aww  = (const float*)d_in[24];
    const float* awb  = (const float*)d_in[25];
    const float* valw = (const float*)d_in[26];
    const float* valb = (const float*)d_in[27];
    const float* ojw  = (const float*)d_in[28];
    const float* ojb  = (const float*)d_in[29];

    float* ws  = (float*)d_ws;
    float* q   = ws;            // 32768
    float* k   = ws + 32768;    // 32768
    float* v   = ws + 65536;    // 32768
    float* x1  = ws + 98304;    // 32768
    float* aw  = ws + 131072;   // 49152
    float* loc = ws + 180224;   // 98304
    float* ca  = ws + 278528;   // 98304
    int*   lxly = (int*)(ws + 376832); // 3072 ints

    k_qkv<<<128, 256, 0, stream>>>(tgt, qpos, ipw, ipb, q, k, v);
    k_attn_norm<<<128, 256, 0, stream>>>(q, k, v, tgt, opw, opb, n2w, n2b, x1);
    k_geo_nq_offaw<<<384, 256, 0, stream>>>(ec, x1, qpos, l0w, l0b, offw, offb, aww, awb, vr, aw, loc, lxly);
    k_sample<<<3072, 256, 0, stream>>>(aw, loc, lxly, src, mask, valw, valb, ca);
    k_tail<<<128, 256, 0, stream>>>(ca, x1, ojw, ojb, n1w, n1b, l1w, l1b, l2w, l2b, n3w, n3b, (float*)d_out);
}